// Round 1
// baseline (5104.809 us; speedup 1.0000x reference)
//
#include <hip/hip_runtime.h>

#define FD 64           // feature dim D = A = G = 64
#define NSLOPE 0.01f

__device__ __forceinline__ float lrelu(float v) { return v > 0.f ? v : NSLOPE * v; }

// order-preserving encode: uint compare order == float compare order
__device__ __forceinline__ unsigned enc_f32(float f) {
    unsigned u = __float_as_uint(f);
    return (u & 0x80000000u) ? ~u : (u | 0x80000000u);
}
__device__ __forceinline__ float dec_f32(unsigned u) {
    return (u & 0x80000000u) ? __uint_as_float(u & 0x7FFFFFFFu) : __uint_as_float(~u);
}

// K1: p_enc = enc(x @ Wm + bm)   [N,64] -> u32
__global__ void k_proj(const float* __restrict__ x, const float* __restrict__ Wm,
                       const float* __restrict__ bm, unsigned* __restrict__ p_enc, int N)
{
    int n = blockIdx.x * blockDim.x + threadIdx.x;
    if (n >= N) return;
    const float* xr = x + (size_t)n * FD;
    float acc[FD];
#pragma unroll
    for (int j = 0; j < FD; ++j) acc[j] = bm[j];
    for (int kt = 0; kt < FD / 8; ++kt) {
        float4 a = *(const float4*)(xr + kt * 8);
        float4 b = *(const float4*)(xr + kt * 8 + 4);
        float z8[8] = {a.x, a.y, a.z, a.w, b.x, b.y, b.z, b.w};
#pragma unroll
        for (int kk = 0; kk < 8; ++kk) {
            const float* wrow = Wm + (kt * 8 + kk) * FD;
#pragma unroll
            for (int j = 0; j < FD; ++j) acc[j] += z8[kk] * wrow[j];
        }
    }
    unsigned* pr = p_enc + (size_t)n * FD;
#pragma unroll
    for (int j = 0; j < FD; ++j) pr[j] = enc_f32(acc[j]);
}

// K2: agg_enc[dst] = max(agg_enc[dst], p_enc[src])  -- 16 threads/edge, 4 chans each
__global__ void k_scatter(const int* __restrict__ src, const int* __restrict__ dst,
                          const uint4* __restrict__ p_enc4, unsigned* __restrict__ agg_enc,
                          int E)
{
    int idx = blockIdx.x * blockDim.x + threadIdx.x;
    int e = idx >> 4, q = idx & 15;
    if (e >= E) return;
    int s = src[e], d = dst[e];
    uint4 v = p_enc4[(size_t)s * 16 + q];
    unsigned* a = agg_enc + (size_t)d * FD + q * 4;
    atomicMax(a + 0, v.x);
    atomicMax(a + 1, v.y);
    atomicMax(a + 2, v.z);
    atomicMax(a + 3, v.w);
}

// K3: x' = lrelu([x, xg_b, lrelu(max-agg)] @ Wa + ba) + x ; gate ; per-graph gate max ;
//     feat = lrelu(x' @ Wfeat + bfeat)
__global__ void k_node(const float* __restrict__ x_in, float* __restrict__ x_out,
                       const float* __restrict__ xg, const int* __restrict__ batch,
                       const unsigned* __restrict__ agg_enc,
                       const float* __restrict__ Wa, const float* __restrict__ ba,
                       const float* __restrict__ Wgate, const float* __restrict__ bgate,
                       const float* __restrict__ Wfeat, const float* __restrict__ bfeat,
                       float* __restrict__ gate_out, float* __restrict__ feat_out,
                       unsigned* __restrict__ gmax_enc, int N)
{
    __shared__ unsigned lmax[16];
    int tid = threadIdx.x;
    if (tid < 16) lmax[tid] = 0u;
    __syncthreads();
    int n = blockIdx.x * blockDim.x + tid;
    if (n < N) {
        int g = batch[n];
        const float* xr  = x_in + (size_t)n * FD;
        const float* xgr = xg + (size_t)g * FD;
        const unsigned* ar = agg_enc + (size_t)n * FD;
        float acc[FD];
#pragma unroll
        for (int j = 0; j < FD; ++j) acc[j] = ba[j];
        // z segment 0: x
        for (int kt = 0; kt < 8; ++kt) {
            float4 a = *(const float4*)(xr + kt * 8);
            float4 b = *(const float4*)(xr + kt * 8 + 4);
            float z8[8] = {a.x, a.y, a.z, a.w, b.x, b.y, b.z, b.w};
#pragma unroll
            for (int kk = 0; kk < 8; ++kk) {
                const float* wrow = Wa + (kt * 8 + kk) * FD;
#pragma unroll
                for (int j = 0; j < FD; ++j) acc[j] += z8[kk] * wrow[j];
            }
        }
        // z segment 1: x_global[batch]
        for (int kt = 0; kt < 8; ++kt) {
            float4 a = *(const float4*)(xgr + kt * 8);
            float4 b = *(const float4*)(xgr + kt * 8 + 4);
            float z8[8] = {a.x, a.y, a.z, a.w, b.x, b.y, b.z, b.w};
#pragma unroll
            for (int kk = 0; kk < 8; ++kk) {
                const float* wrow = Wa + (64 + kt * 8 + kk) * FD;
#pragma unroll
                for (int j = 0; j < FD; ++j) acc[j] += z8[kk] * wrow[j];
            }
        }
        // z segment 2: agg (decode, empty->0, lrelu after max)
        for (int kt = 0; kt < 8; ++kt) {
            uint4 a = *(const uint4*)(ar + kt * 8);
            uint4 b = *(const uint4*)(ar + kt * 8 + 4);
            unsigned u8[8] = {a.x, a.y, a.z, a.w, b.x, b.y, b.z, b.w};
            float z8[8];
#pragma unroll
            for (int kk = 0; kk < 8; ++kk)
                z8[kk] = (u8[kk] == 0u) ? 0.f : lrelu(dec_f32(u8[kk]));
#pragma unroll
            for (int kk = 0; kk < 8; ++kk) {
                const float* wrow = Wa + (128 + kt * 8 + kk) * FD;
#pragma unroll
                for (int j = 0; j < FD; ++j) acc[j] += z8[kk] * wrow[j];
            }
        }
        // finish node update + gate
        float gv = bgate[0];
        float* xo = x_out + (size_t)n * FD;
#pragma unroll
        for (int j = 0; j < FD; ++j) {
            float v = lrelu(acc[j]) + xr[j];
            xo[j] = v;
            gv += v * Wgate[j];
        }
        gate_out[n] = gv;
        atomicMax(&lmax[g], enc_f32(gv));
        // feat = lrelu(x' @ Wfeat + bfeat)
        float acc2[FD];
#pragma unroll
        for (int j = 0; j < FD; ++j) acc2[j] = bfeat[j];
        for (int kt = 0; kt < 8; ++kt) {
            float4 a = *(const float4*)(xo + kt * 8);
            float4 b = *(const float4*)(xo + kt * 8 + 4);
            float z8[8] = {a.x, a.y, a.z, a.w, b.x, b.y, b.z, b.w};
#pragma unroll
            for (int kk = 0; kk < 8; ++kk) {
                const float* wrow = Wfeat + (kt * 8 + kk) * FD;
#pragma unroll
                for (int j = 0; j < FD; ++j) acc2[j] += z8[kk] * wrow[j];
            }
        }
        float* fo = feat_out + (size_t)n * FD;
#pragma unroll
        for (int j = 0; j < FD; ++j) fo[j] = lrelu(acc2[j]);
    }
    __syncthreads();
    if (tid < 16 && lmax[tid] != 0u) atomicMax(&gmax_enc[tid], lmax[tid]);
}

// K4: per-graph  sum_e = Σ exp(gate-gmax),  V = Σ exp(gate-gmax)*feat
// wave-per-chunk, lane == feature column; sorted batch_ind -> rare flushes
__global__ void k_pool(const float* __restrict__ gate, const float* __restrict__ feat,
                       const int* __restrict__ batch, const unsigned* __restrict__ gmax_enc,
                       float* __restrict__ sum_e, float* __restrict__ Vv, int N)
{
    int gid = blockIdx.x * blockDim.x + threadIdx.x;
    int wave = gid >> 6;
    int lane = threadIdx.x & 63;
    int nwaves = (gridDim.x * blockDim.x) >> 6;
    int chunk = (N + nwaves - 1) / nwaves;
    int n0 = wave * chunk;
    int n1 = min(N, n0 + chunk);
    if (n0 >= n1) return;
    int gcur = batch[n0];
    float gm = dec_f32(gmax_enc[gcur]);
    float accv = 0.f, acce = 0.f;
    for (int n = n0; n < n1; ++n) {
        int g = batch[n];
        if (g != gcur) {
            atomicAdd(&Vv[gcur * FD + lane], accv);
            if (lane == 0) atomicAdd(&sum_e[gcur], acce);
            gcur = g;
            gm = dec_f32(gmax_enc[g]);
            accv = 0.f; acce = 0.f;
        }
        float e = __expf(gate[n] - gm);
        accv += e * feat[(size_t)n * FD + lane];
        acce += e;
    }
    atomicAdd(&Vv[gcur * FD + lane], accv);
    if (lane == 0) atomicAdd(&sum_e[gcur], acce);
}

// K5: x_global' = lrelu([V/sum_e, x_global] @ Wt + bt) + x_global  (one block)
__global__ void k_global(const float* __restrict__ xg_in, float* __restrict__ xg_out,
                         const float* __restrict__ Vv, const float* __restrict__ sum_e,
                         const float* __restrict__ Wt, const float* __restrict__ bt, int NG)
{
    __shared__ float xgold[1024], xgn[1024];
    int tid = threadIdx.x;
    int tot = NG * FD;
    if (tid < tot) {
        xgold[tid] = xg_in[tid];
        xgn[tid] = Vv[tid] / sum_e[tid >> 6];
    }
    __syncthreads();
    if (tid >= tot) return;
    int g = tid >> 6, j = tid & 63;
    float acc = bt[j];
    for (int k = 0; k < FD; ++k) acc += xgn[g * FD + k] * Wt[k * FD + j];
    for (int k = 0; k < FD; ++k) acc += xgold[g * FD + k] * Wt[(FD + k) * FD + j];
    xg_out[tid] = lrelu(acc) + xgold[tid];
}

extern "C" void kernel_launch(void* const* d_in, const int* in_sizes, int n_in,
                              void* d_out, int out_size, void* d_ws, size_t ws_size,
                              hipStream_t stream)
{
    const float* x0     = (const float*)d_in[0];
    const float* xg0    = (const float*)d_in[1];
    const int*   ei     = (const int*)d_in[3];
    const int*   batch  = (const int*)d_in[4];
    const float* Wm     = (const float*)d_in[6];
    const float* bm     = (const float*)d_in[7];
    const float* Wa     = (const float*)d_in[8];
    const float* ba     = (const float*)d_in[9];
    const float* Wgate  = (const float*)d_in[10];
    const float* bgate  = (const float*)d_in[11];
    const float* Wfeat  = (const float*)d_in[12];
    const float* bfeat  = (const float*)d_in[13];
    const float* Wt     = (const float*)d_in[14];
    const float* bt     = (const float*)d_in[15];

    const int N  = in_sizes[0] / FD;
    const int E  = in_sizes[3] / 2;
    const int NG = in_sizes[1] / FD;
    const int S  = in_sizes[6] / (FD * FD);

    float* x_out  = (float*)d_out;
    float* xg_out = (float*)d_out + (size_t)N * FD;

    char* ws = (char*)d_ws;
    const size_t aggB   = (size_t)N * FD * 4;
    const size_t smallB = 8192;
    unsigned* agg_enc  = (unsigned*)ws;
    unsigned* gmax_enc = (unsigned*)(ws + aggB);
    float*    sum_e    = (float*)(ws + aggB + 256);
    float*    Vv       = (float*)(ws + aggB + 512);
    unsigned* p_enc    = (unsigned*)(ws + aggB + smallB);
    float*    feat     = (float*)p_enc;               // reuse: p dead before feat written
    float*    gate     = (float*)(ws + aggB + smallB + aggB);

    const float* x_in  = x0;
    const float* xg_in = xg0;

    const int nb_node = (N + 255) / 256;
    const long long sc_threads = (long long)E * 16;
    const int nb_sc = (int)((sc_threads + 255) / 256);

    for (int i = 0; i < S; ++i) {
        hipMemsetAsync(ws, 0, aggB + smallB, stream);   // agg "empty" + gmax/sum_e/V = 0
        k_proj<<<nb_node, 256, 0, stream>>>(x_in, Wm + i * FD * FD, bm + i * FD, p_enc, N);
        k_scatter<<<nb_sc, 256, 0, stream>>>(ei, ei + E, (const uint4*)p_enc, agg_enc, E);
        k_node<<<nb_node, 256, 0, stream>>>(x_in, x_out, xg_in, batch, agg_enc,
                                            Wa + (size_t)i * 192 * FD, ba + i * FD,
                                            Wgate + i * FD, bgate + i,
                                            Wfeat + i * FD * FD, bfeat + i * FD,
                                            gate, feat, gmax_enc, N);
        k_pool<<<256, 256, 0, stream>>>(gate, feat, batch, gmax_enc, sum_e, Vv, N);
        k_global<<<1, NG * FD, 0, stream>>>(xg_in, xg_out, Vv, sum_e,
                                            Wt + (size_t)i * 2 * FD * FD, bt + i * FD, NG);
        x_in  = x_out;
        xg_in = xg_out;
    }
}

// Round 2
// 1361.370 us; speedup vs baseline: 3.7498x; 3.7498x over previous
//
#include <hip/hip_runtime.h>

#define FD 64           // feature dim D = A = G = 64
#define NSLOPE 0.01f
#define SCAN_BS 1024

__device__ __forceinline__ float lrelu(float v) { return v > 0.f ? v : NSLOPE * v; }

// order-preserving encode for the (tiny) per-graph gate max
__device__ __forceinline__ unsigned enc_f32(float f) {
    unsigned u = __float_as_uint(f);
    return (u & 0x80000000u) ? ~u : (u | 0x80000000u);
}
__device__ __forceinline__ float dec_f32(unsigned u) {
    return (u & 0x80000000u) ? __uint_as_float(u & 0x7FFFFFFFu) : __uint_as_float(~u);
}

// ---------------- preprocessing: CSR by dst (once per launch) ----------------

__global__ void k_hist(const int* __restrict__ dst, int* __restrict__ deg, int E)
{
    int e = blockIdx.x * blockDim.x + threadIdx.x;
    if (e < E) atomicAdd(&deg[dst[e]], 1);
}

__global__ void k_scan1(const int* __restrict__ deg, int* __restrict__ off,
                        int* __restrict__ bsums, int N)
{
    __shared__ int tmp[SCAN_BS];
    int t = threadIdx.x, b = blockIdx.x;
    int i = b * SCAN_BS + t;
    int v = (i < N) ? deg[i] : 0;
    tmp[t] = v;
    __syncthreads();
    for (int d = 1; d < SCAN_BS; d <<= 1) {
        int add = (t >= d) ? tmp[t - d] : 0;
        __syncthreads();
        tmp[t] += add;
        __syncthreads();
    }
    if (i < N) off[i] = tmp[t] - v;          // exclusive
    if (t == SCAN_BS - 1) bsums[b] = tmp[t]; // block total
}

__global__ void k_scan2(int* __restrict__ bsums, int nb)
{
    __shared__ int tmp[SCAN_BS];
    int t = threadIdx.x;
    int v = (t < nb) ? bsums[t] : 0;
    tmp[t] = v;
    __syncthreads();
    for (int d = 1; d < SCAN_BS; d <<= 1) {
        int add = (t >= d) ? tmp[t - d] : 0;
        __syncthreads();
        tmp[t] += add;
        __syncthreads();
    }
    if (t < nb) bsums[t] = tmp[t] - v;       // exclusive over blocks
}

// finalize off, and seed cursor (=off); after k_place cursor[n] == bucket end
__global__ void k_scan3(int* __restrict__ off, const int* __restrict__ bsums,
                        int* __restrict__ cursor, int N)
{
    int i = blockIdx.x * blockDim.x + threadIdx.x;
    if (i < N) {
        int o = off[i] + bsums[i >> 10];
        off[i] = o;
        cursor[i] = o;
    }
}

__global__ void k_place(const int* __restrict__ src, const int* __restrict__ dst,
                        int* __restrict__ cursor, int* __restrict__ esrc, int E)
{
    int e = blockIdx.x * blockDim.x + threadIdx.x;
    if (e >= E) return;
    int pos = atomicAdd(&cursor[dst[e]], 1);
    esrc[pos] = src[e];
}

// ---------------- per-step kernels ----------------

// K1: p = x @ Wm + bm   (plain float, lrelu deferred past the max)
__global__ void k_proj(const float* __restrict__ x, const float* __restrict__ Wm,
                       const float* __restrict__ bm, float* __restrict__ p, int N)
{
    int n = blockIdx.x * blockDim.x + threadIdx.x;
    if (n >= N) return;
    const float* xr = x + (size_t)n * FD;
    float acc[FD];
#pragma unroll
    for (int j = 0; j < FD; ++j) acc[j] = bm[j];
    for (int kt = 0; kt < FD / 8; ++kt) {
        float4 a = *(const float4*)(xr + kt * 8);
        float4 b = *(const float4*)(xr + kt * 8 + 4);
        float z8[8] = {a.x, a.y, a.z, a.w, b.x, b.y, b.z, b.w};
#pragma unroll
        for (int kk = 0; kk < 8; ++kk) {
            const float* wrow = Wm + (kt * 8 + kk) * FD;
#pragma unroll
            for (int j = 0; j < FD; ++j) acc[j] += z8[kk] * wrow[j];
        }
    }
    float* pr = p + (size_t)n * FD;
#pragma unroll
    for (int j = 0; j < FD; ++j) pr[j] = acc[j];
}

// K2: agg[n] = lrelu(max over in-edges of p[src]); empty -> 0.  16 thr/node.
__global__ void k_agg(const float4* __restrict__ p4, const int* __restrict__ off,
                      const int* __restrict__ endp, const int* __restrict__ esrc,
                      float4* __restrict__ agg4, int N)
{
    int tid = threadIdx.x;
    int q = tid & 15;
    int n = blockIdx.x * 16 + (tid >> 4);
    if (n >= N) return;
    int j0 = off[n], j1 = endp[n];
    float4 m = make_float4(-__builtin_inff(), -__builtin_inff(),
                           -__builtin_inff(), -__builtin_inff());
    int j = j0;
    for (; j + 1 < j1; j += 2) {
        int s0 = esrc[j], s1 = esrc[j + 1];
        float4 v0 = p4[(size_t)s0 * 16 + q];
        float4 v1 = p4[(size_t)s1 * 16 + q];
        m.x = fmaxf(m.x, v0.x); m.y = fmaxf(m.y, v0.y);
        m.z = fmaxf(m.z, v0.z); m.w = fmaxf(m.w, v0.w);
        m.x = fmaxf(m.x, v1.x); m.y = fmaxf(m.y, v1.y);
        m.z = fmaxf(m.z, v1.z); m.w = fmaxf(m.w, v1.w);
    }
    if (j < j1) {
        int s0 = esrc[j];
        float4 v0 = p4[(size_t)s0 * 16 + q];
        m.x = fmaxf(m.x, v0.x); m.y = fmaxf(m.y, v0.y);
        m.z = fmaxf(m.z, v0.z); m.w = fmaxf(m.w, v0.w);
    }
    float4 o;
    if (j0 == j1) o = make_float4(0.f, 0.f, 0.f, 0.f);
    else { o.x = lrelu(m.x); o.y = lrelu(m.y); o.z = lrelu(m.z); o.w = lrelu(m.w); }
    agg4[(size_t)n * 16 + q] = o;
}

// K3: x' = lrelu([x, xg_b, agg] @ Wa + ba) + x ; gate ; per-graph gate max ;
//     feat = lrelu(x' @ Wfeat + bfeat)
__global__ void k_node(const float* __restrict__ x_in, float* __restrict__ x_out,
                       const float* __restrict__ xg, const int* __restrict__ batch,
                       const float* __restrict__ agg,
                       const float* __restrict__ Wa, const float* __restrict__ ba,
                       const float* __restrict__ Wgate, const float* __restrict__ bgate,
                       const float* __restrict__ Wfeat, const float* __restrict__ bfeat,
                       float* __restrict__ gate_out, float* __restrict__ feat_out,
                       unsigned* __restrict__ gmax_enc, int N)
{
    __shared__ unsigned lmax[16];
    int tid = threadIdx.x;
    if (tid < 16) lmax[tid] = 0u;
    __syncthreads();
    int n = blockIdx.x * blockDim.x + tid;
    if (n < N) {
        int g = batch[n];
        const float* xr  = x_in + (size_t)n * FD;
        const float* xgr = xg + (size_t)g * FD;
        const float* ar  = agg + (size_t)n * FD;
        float acc[FD];
#pragma unroll
        for (int j = 0; j < FD; ++j) acc[j] = ba[j];
        // z segment 0: x
        for (int kt = 0; kt < 8; ++kt) {
            float4 a = *(const float4*)(xr + kt * 8);
            float4 b = *(const float4*)(xr + kt * 8 + 4);
            float z8[8] = {a.x, a.y, a.z, a.w, b.x, b.y, b.z, b.w};
#pragma unroll
            for (int kk = 0; kk < 8; ++kk) {
                const float* wrow = Wa + (kt * 8 + kk) * FD;
#pragma unroll
                for (int j = 0; j < FD; ++j) acc[j] += z8[kk] * wrow[j];
            }
        }
        // z segment 1: x_global[batch]
        for (int kt = 0; kt < 8; ++kt) {
            float4 a = *(const float4*)(xgr + kt * 8);
            float4 b = *(const float4*)(xgr + kt * 8 + 4);
            float z8[8] = {a.x, a.y, a.z, a.w, b.x, b.y, b.z, b.w};
#pragma unroll
            for (int kk = 0; kk < 8; ++kk) {
                const float* wrow = Wa + (64 + kt * 8 + kk) * FD;
#pragma unroll
                for (int j = 0; j < FD; ++j) acc[j] += z8[kk] * wrow[j];
            }
        }
        // z segment 2: agg
        for (int kt = 0; kt < 8; ++kt) {
            float4 a = *(const float4*)(ar + kt * 8);
            float4 b = *(const float4*)(ar + kt * 8 + 4);
            float z8[8] = {a.x, a.y, a.z, a.w, b.x, b.y, b.z, b.w};
#pragma unroll
            for (int kk = 0; kk < 8; ++kk) {
                const float* wrow = Wa + (128 + kt * 8 + kk) * FD;
#pragma unroll
                for (int j = 0; j < FD; ++j) acc[j] += z8[kk] * wrow[j];
            }
        }
        // finish node update + gate
        float gv = bgate[0];
        float* xo = x_out + (size_t)n * FD;
#pragma unroll
        for (int j = 0; j < FD; ++j) {
            float v = lrelu(acc[j]) + xr[j];
            xo[j] = v;
            gv += v * Wgate[j];
        }
        gate_out[n] = gv;
        atomicMax(&lmax[g], enc_f32(gv));
        // feat = lrelu(x' @ Wfeat + bfeat)
        float acc2[FD];
#pragma unroll
        for (int j = 0; j < FD; ++j) acc2[j] = bfeat[j];
        for (int kt = 0; kt < 8; ++kt) {
            float4 a = *(const float4*)(xo + kt * 8);
            float4 b = *(const float4*)(xo + kt * 8 + 4);
            float z8[8] = {a.x, a.y, a.z, a.w, b.x, b.y, b.z, b.w};
#pragma unroll
            for (int kk = 0; kk < 8; ++kk) {
                const float* wrow = Wfeat + (kt * 8 + kk) * FD;
#pragma unroll
                for (int j = 0; j < FD; ++j) acc2[j] += z8[kk] * wrow[j];
            }
        }
        float* fo = feat_out + (size_t)n * FD;
#pragma unroll
        for (int j = 0; j < FD; ++j) fo[j] = lrelu(acc2[j]);
    }
    __syncthreads();
    if (tid < 16 && lmax[tid] != 0u) atomicMax(&gmax_enc[tid], lmax[tid]);
}

// K4: per-graph  sum_e = sum exp(gate-gmax),  V = sum exp(gate-gmax)*feat
__global__ void k_pool(const float* __restrict__ gate, const float* __restrict__ feat,
                       const int* __restrict__ batch, const unsigned* __restrict__ gmax_enc,
                       float* __restrict__ sum_e, float* __restrict__ Vv, int N)
{
    int gid = blockIdx.x * blockDim.x + threadIdx.x;
    int wave = gid >> 6;
    int lane = threadIdx.x & 63;
    int nwaves = (gridDim.x * blockDim.x) >> 6;
    int chunk = (N + nwaves - 1) / nwaves;
    int n0 = wave * chunk;
    int n1 = min(N, n0 + chunk);
    if (n0 >= n1) return;
    int gcur = batch[n0];
    float gm = dec_f32(gmax_enc[gcur]);
    float accv = 0.f, acce = 0.f;
    for (int n = n0; n < n1; ++n) {
        int g = batch[n];
        if (g != gcur) {
            atomicAdd(&Vv[gcur * FD + lane], accv);
            if (lane == 0) atomicAdd(&sum_e[gcur], acce);
            gcur = g;
            gm = dec_f32(gmax_enc[g]);
            accv = 0.f; acce = 0.f;
        }
        float e = __expf(gate[n] - gm);
        accv += e * feat[(size_t)n * FD + lane];
        acce += e;
    }
    atomicAdd(&Vv[gcur * FD + lane], accv);
    if (lane == 0) atomicAdd(&sum_e[gcur], acce);
}

// K5: x_global' = lrelu([V/sum_e, x_global] @ Wt + bt) + x_global  (one block)
__global__ void k_global(const float* __restrict__ xg_in, float* __restrict__ xg_out,
                         const float* __restrict__ Vv, const float* __restrict__ sum_e,
                         const float* __restrict__ Wt, const float* __restrict__ bt, int NG)
{
    __shared__ float xgold[1024], xgn[1024];
    int tid = threadIdx.x;
    int tot = NG * FD;
    if (tid < tot) {
        xgold[tid] = xg_in[tid];
        xgn[tid] = Vv[tid] / sum_e[tid >> 6];
    }
    __syncthreads();
    if (tid >= tot) return;
    int g = tid >> 6, j = tid & 63;
    float acc = bt[j];
    for (int k = 0; k < FD; ++k) acc += xgn[g * FD + k] * Wt[k * FD + j];
    for (int k = 0; k < FD; ++k) acc += xgold[g * FD + k] * Wt[(FD + k) * FD + j];
    xg_out[tid] = lrelu(acc) + xgold[tid];
}

extern "C" void kernel_launch(void* const* d_in, const int* in_sizes, int n_in,
                              void* d_out, int out_size, void* d_ws, size_t ws_size,
                              hipStream_t stream)
{
    const float* x0     = (const float*)d_in[0];
    const float* xg0    = (const float*)d_in[1];
    const int*   ei     = (const int*)d_in[3];
    const int*   batch  = (const int*)d_in[4];
    const float* Wm     = (const float*)d_in[6];
    const float* bm     = (const float*)d_in[7];
    const float* Wa     = (const float*)d_in[8];
    const float* ba     = (const float*)d_in[9];
    const float* Wgate  = (const float*)d_in[10];
    const float* bgate  = (const float*)d_in[11];
    const float* Wfeat  = (const float*)d_in[12];
    const float* bfeat  = (const float*)d_in[13];
    const float* Wt     = (const float*)d_in[14];
    const float* bt     = (const float*)d_in[15];

    const int N  = in_sizes[0] / FD;
    const int E  = in_sizes[3] / 2;
    const int NG = in_sizes[1] / FD;
    const int S  = in_sizes[6] / (FD * FD);

    const int* esrc_in = ei;       // edge_index[0]
    const int* edst_in = ei + E;   // edge_index[1]

    float* x_out  = (float*)d_out;
    float* xg_out = (float*)d_out + (size_t)N * FD;

    // ---- workspace layout ----
    char* ws = (char*)d_ws;
    const size_t rowB = (size_t)N * FD * 4;          // 25.6 MB
    float* agg   = (float*)ws;                        // [N,64]
    float* p     = (float*)(ws + rowB);               // [N,64]; feat aliases p
    float* feat  = p;
    int*   esrc  = (int*)(ws + 2 * rowB);             // [E] CSR-ordered srcs
    int*   off   = (int*)(ws + 2 * rowB + (size_t)E * 4);  // [N]
    int*   endp  = off + N;                           // cursor -> bucket ends
    int*   deg   = endp + N;                          // [N]; gate aliases deg
    float* gate  = (float*)deg;
    int*   bsums = deg + N;                           // [1024]
    unsigned* gmax_enc = (unsigned*)(bsums + 1024);   // [16] (padded 64)
    float* sum_e = (float*)(gmax_enc + 64);           // [16] (padded 64)
    float* Vv    = sum_e + 64;                        // [16*64]

    const int nb_node = (N + 255) / 256;
    const int nb_edge = (E + 255) / 256;
    const int nb_scan = (N + SCAN_BS - 1) / SCAN_BS;
    const int nb_agg  = (N + 15) / 16;

    // ---- preprocessing: CSR by dst (edge_index constant across steps) ----
    hipMemsetAsync(deg, 0, (size_t)N * 4, stream);
    k_hist <<<nb_edge, 256, 0, stream>>>(edst_in, deg, E);
    k_scan1<<<nb_scan, SCAN_BS, 0, stream>>>(deg, off, bsums, N);
    k_scan2<<<1, SCAN_BS, 0, stream>>>(bsums, nb_scan);
    k_scan3<<<nb_node, 256, 0, stream>>>(off, bsums, endp, N);
    k_place<<<nb_edge, 256, 0, stream>>>(esrc_in, edst_in, endp, esrc, E);

    const float* x_in  = x0;
    const float* xg_in = xg0;

    for (int i = 0; i < S; ++i) {
        hipMemsetAsync(gmax_enc, 0, (64 + 64 + 1024) * 4, stream);
        k_proj<<<nb_node, 256, 0, stream>>>(x_in, Wm + i * FD * FD, bm + i * FD, p, N);
        k_agg <<<nb_agg, 256, 0, stream>>>((const float4*)p, off, endp, esrc,
                                           (float4*)agg, N);
        k_node<<<nb_node, 256, 0, stream>>>(x_in, x_out, xg_in, batch, agg,
                                            Wa + (size_t)i * 192 * FD, ba + i * FD,
                                            Wgate + i * FD, bgate + i,
                                            Wfeat + i * FD * FD, bfeat + i * FD,
                                            gate, feat, gmax_enc, N);
        k_pool<<<256, 256, 0, stream>>>(gate, feat, batch, gmax_enc, sum_e, Vv, N);
        k_global<<<1, NG * FD, 0, stream>>>(xg_in, xg_out, Vv, sum_e,
                                            Wt + (size_t)i * 2 * FD * FD, bt + i * FD, NG);
        x_in  = x_out;
        xg_in = xg_out;
    }
}